// Round 1
// baseline (137.289 us; speedup 1.0000x reference)
//
#include <hip/hip_runtime.h>

#define EMB 300

// Kernel 1: per-vocab-row dot products with the two halves of W.
// One wave (64 lanes) per row; coalesced 4B loads; shuffle reduce.
__global__ void dot_kernel(const float* __restrict__ emb,
                           const float* __restrict__ W,
                           float* __restrict__ dotA,
                           float* __restrict__ dotB,
                           int vocab) {
    __shared__ float sW[2 * EMB];
    for (int i = threadIdx.x; i < 2 * EMB; i += blockDim.x) sW[i] = W[i];
    __syncthreads();

    int gtid   = blockIdx.x * blockDim.x + threadIdx.x;
    int wave   = gtid >> 6;
    int lane   = threadIdx.x & 63;
    int nwaves = (gridDim.x * blockDim.x) >> 6;

    for (int row = wave; row < vocab; row += nwaves) {
        const float* e = emb + (size_t)row * EMB;
        float a = 0.f, bsum = 0.f;
        for (int k = lane; k < EMB; k += 64) {
            float v = e[k];
            a    += v * sW[k];
            bsum += v * sW[EMB + k];
        }
        // wave64 butterfly reduce
        for (int off = 32; off > 0; off >>= 1) {
            a    += __shfl_down(a, off, 64);
            bsum += __shfl_down(bsum, off, 64);
        }
        if (lane == 0) {
            dotA[row] = a;
            dotB[row] = bsum;
        }
    }
}

// Kernel 2: per-token scalar lookup + segment accumulation via atomics.
__global__ void seg_kernel(const int* __restrict__ token_ids,
                           const int* __restrict__ segment_ids,
                           const float* __restrict__ dotA,
                           const float* __restrict__ dotB,
                           float* __restrict__ sums,
                           float* __restrict__ counts,
                           int T) {
    int i      = blockIdx.x * blockDim.x + threadIdx.x;
    int stride = gridDim.x * blockDim.x;
    for (; i < T; i += stride) {
        int s   = segment_ids[i];
        int tok = token_ids[i];
        float v = (s & 1) ? dotB[tok] : dotA[tok];
        atomicAdd(&sums[s], v);
        atomicAdd(&counts[s], 1.0f);
    }
}

// Kernel 3: combine pair of segment means + bias, sigmoid.
__global__ void out_kernel(const float* __restrict__ sums,
                           const float* __restrict__ counts,
                           const float* __restrict__ bptr,
                           float* __restrict__ out,
                           int pairs) {
    int p = blockIdx.x * blockDim.x + threadIdx.x;
    if (p >= pairs) return;
    int s0 = 2 * p, s1 = 2 * p + 1;
    float m0 = sums[s0] / fmaxf(counts[s0], 1.0f);
    float m1 = sums[s1] / fmaxf(counts[s1], 1.0f);
    float logit = m0 + m1 + bptr[0];
    out[p] = 1.0f / (1.0f + expf(-logit));
}

extern "C" void kernel_launch(void* const* d_in, const int* in_sizes, int n_in,
                              void* d_out, int out_size, void* d_ws, size_t ws_size,
                              hipStream_t stream) {
    const float* emb         = (const float*)d_in[0];
    const float* W           = (const float*)d_in[1];
    const float* b           = (const float*)d_in[2];
    const int*   token_ids   = (const int*)d_in[3];
    const int*   segment_ids = (const int*)d_in[4];

    const int T            = in_sizes[3];
    const int vocab        = in_sizes[0] / EMB;
    const int pairs        = out_size;
    const int num_segments = pairs * 2;

    float* dotA   = (float*)d_ws;
    float* dotB   = dotA + vocab;
    float* sums   = dotB + vocab;
    float* counts = sums + num_segments;

    // zero the accumulators each call (harness does not re-poison between replays)
    hipMemsetAsync(sums, 0, sizeof(float) * (size_t)num_segments * 2, stream);

    // Kernel 1: 2048 blocks x 256 = 8192 waves, grid-stride over 100000 rows.
    dot_kernel<<<2048, 256, 0, stream>>>(emb, W, dotA, dotB, vocab);
    // Kernel 2: 655360 tokens.
    seg_kernel<<<1024, 256, 0, stream>>>(token_ids, segment_ids, dotA, dotB,
                                         sums, counts, T);
    // Kernel 3: 16384 pairs.
    out_kernel<<<(pairs + 255) / 256, 256, 0, stream>>>(sums, counts, b,
                                                        (float*)d_out, pairs);
}

// Round 2
// 55.806 us; speedup vs baseline: 2.4601x; 2.4601x over previous
//
#include <hip/hip_runtime.h>

#define EMB 300
#define EMB4 75  // 300/4

// Kernel 1: per-vocab-row dot products with the two halves of W.
// One wave (64 lanes) per row; float4 coalesced loads; shuffle reduce.
__global__ void dot_kernel(const float* __restrict__ emb,
                           const float* __restrict__ W,
                           float* __restrict__ dotA,
                           float* __restrict__ dotB,
                           int vocab) {
    __shared__ float4 sWA[EMB4];
    __shared__ float4 sWB[EMB4];
    const float4* W4 = (const float4*)W;  // 600 floats = 150 float4
    for (int i = threadIdx.x; i < EMB4; i += blockDim.x) {
        sWA[i] = W4[i];
        sWB[i] = W4[EMB4 + i];
    }
    __syncthreads();

    int gtid   = blockIdx.x * blockDim.x + threadIdx.x;
    int wave   = gtid >> 6;
    int lane   = threadIdx.x & 63;
    int nwaves = (gridDim.x * blockDim.x) >> 6;

    for (int row = wave; row < vocab; row += nwaves) {
        const float4* e4 = (const float4*)(emb + (size_t)row * EMB);  // 1200B rows: 16B aligned
        float a = 0.f, bsum = 0.f;
        for (int k = lane; k < EMB4; k += 64) {
            float4 v  = e4[k];
            float4 wa = sWA[k];
            float4 wb = sWB[k];
            a    += v.x * wa.x + v.y * wa.y + v.z * wa.z + v.w * wa.w;
            bsum += v.x * wb.x + v.y * wb.y + v.z * wb.z + v.w * wb.w;
        }
        for (int off = 32; off > 0; off >>= 1) {
            a    += __shfl_down(a, off, 64);
            bsum += __shfl_down(bsum, off, 64);
        }
        if (lane == 0) {
            dotA[row] = a;
            dotB[row] = bsum;
        }
    }
}

__device__ __forceinline__ int lower_bound(const int* __restrict__ a, int n, int x) {
    int lo = 0, hi = n;
    while (lo < hi) {
        int mid = (lo + hi) >> 1;
        if (a[mid] < x) lo = mid + 1; else hi = mid;
    }
    return lo;
}

// Kernel 2: one thread per output pair. segment_ids is sorted, so segment
// boundaries come from binary search — no atomics, no accumulator arrays.
__global__ void pair_kernel(const int* __restrict__ token_ids,
                            const int* __restrict__ segment_ids,
                            const float* __restrict__ dotA,
                            const float* __restrict__ dotB,
                            const float* __restrict__ bptr,
                            float* __restrict__ out,
                            int T, int pairs) {
    int p = blockIdx.x * blockDim.x + threadIdx.x;
    if (p >= pairs) return;
    int s0 = 2 * p;
    int i0 = lower_bound(segment_ids, T, s0);
    int i1 = lower_bound(segment_ids, T, s0 + 1);
    int i2 = lower_bound(segment_ids, T, s0 + 2);

    float sA = 0.f;
    for (int j = i0; j < i1; ++j) sA += dotA[token_ids[j]];
    float sB = 0.f;
    for (int j = i1; j < i2; ++j) sB += dotB[token_ids[j]];

    float m0 = sA / fmaxf((float)(i1 - i0), 1.0f);
    float m1 = sB / fmaxf((float)(i2 - i1), 1.0f);
    float logit = m0 + m1 + bptr[0];
    out[p] = 1.0f / (1.0f + expf(-logit));
}

extern "C" void kernel_launch(void* const* d_in, const int* in_sizes, int n_in,
                              void* d_out, int out_size, void* d_ws, size_t ws_size,
                              hipStream_t stream) {
    const float* emb         = (const float*)d_in[0];
    const float* W           = (const float*)d_in[1];
    const float* b           = (const float*)d_in[2];
    const int*   token_ids   = (const int*)d_in[3];
    const int*   segment_ids = (const int*)d_in[4];

    const int T     = in_sizes[3];
    const int vocab = in_sizes[0] / EMB;
    const int pairs = out_size;

    float* dotA = (float*)d_ws;
    float* dotB = dotA + vocab;

    // Kernel 1: 2048 blocks x 256 = 8192 waves over 100000 rows.
    dot_kernel<<<2048, 256, 0, stream>>>(emb, W, dotA, dotB, vocab);
    // Kernel 2: 16384 pairs, 64-thread blocks so all 256 CUs get work.
    pair_kernel<<<(pairs + 63) / 64, 64, 0, stream>>>(token_ids, segment_ids,
                                                      dotA, dotB, b,
                                                      (float*)d_out, T, pairs);
}

// Round 3
// 46.175 us; speedup vs baseline: 2.9733x; 1.2086x over previous
//
#include <hip/hip_runtime.h>

#define EMB 300
#define EMB4 75  // 300/4

// Kernel 1: per-vocab-row dot products with the two halves of W.
// One wave (64 lanes) per row; float4 coalesced loads; shuffle reduce.
// Memory-bound: reads the full 100000x300 f32 table (120 MB) once.
__global__ void dot_kernel(const float* __restrict__ emb,
                           const float* __restrict__ W,
                           float* __restrict__ dotA,
                           float* __restrict__ dotB,
                           int vocab) {
    __shared__ float4 sWA[EMB4];
    __shared__ float4 sWB[EMB4];
    const float4* W4 = (const float4*)W;  // 600 floats = 150 float4
    for (int i = threadIdx.x; i < EMB4; i += blockDim.x) {
        sWA[i] = W4[i];
        sWB[i] = W4[EMB4 + i];
    }
    __syncthreads();

    int gtid   = blockIdx.x * blockDim.x + threadIdx.x;
    int wave   = gtid >> 6;
    int lane   = threadIdx.x & 63;
    int nwaves = (gridDim.x * blockDim.x) >> 6;

    for (int row = wave; row < vocab; row += nwaves) {
        const float4* e4 = (const float4*)(emb + (size_t)row * EMB);  // 1200B rows, 16B aligned
        float a = 0.f, bsum = 0.f;
        #pragma unroll
        for (int kk = 0; kk < 2; ++kk) {
            int k = lane + kk * 64;
            if (k < EMB4) {
                float4 v  = e4[k];
                float4 wa = sWA[k];
                float4 wb = sWB[k];
                a    += v.x * wa.x + v.y * wa.y + v.z * wa.z + v.w * wa.w;
                bsum += v.x * wb.x + v.y * wb.y + v.z * wb.z + v.w * wb.w;
            }
        }
        for (int off = 32; off > 0; off >>= 1) {
            a    += __shfl_down(a, off, 64);
            bsum += __shfl_down(bsum, off, 64);
        }
        if (lane == 0) {
            dotA[row] = a;
            dotB[row] = bsum;
        }
    }
}

__device__ __forceinline__ int lower_bound(const int* __restrict__ a, int n, int x) {
    int lo = 0, hi = n;
    while (lo < hi) {
        int mid = (lo + hi) >> 1;
        if (a[mid] < x) lo = mid + 1; else hi = mid;
    }
    return lo;
}

// Kernel 2: ONE WAVE per output pair (16384 waves = 64 waves/CU).
// Lanes 0..2 binary-search the three segment boundaries in parallel,
// broadcast, then all 64 lanes cooperatively gather + reduce.
__global__ void pair_kernel(const int* __restrict__ token_ids,
                            const int* __restrict__ segment_ids,
                            const float* __restrict__ dotA,
                            const float* __restrict__ dotB,
                            const float* __restrict__ bptr,
                            float* __restrict__ out,
                            int T, int pairs) {
    int wave = (blockIdx.x * blockDim.x + threadIdx.x) >> 6;
    int lane = threadIdx.x & 63;
    if (wave >= pairs) return;
    int s0 = 2 * wave;

    int bnd = 0;
    if (lane < 3) bnd = lower_bound(segment_ids, T, s0 + lane);
    int i0 = __shfl(bnd, 0, 64);
    int i1 = __shfl(bnd, 1, 64);
    int i2 = __shfl(bnd, 2, 64);

    float sA = 0.f, sB = 0.f;
    for (int j = i0 + lane; j < i2; j += 64) {
        int tok = token_ids[j];
        float vA = dotA[tok];
        float vB = dotB[tok];
        if (j < i1) sA += vA; else sB += vB;
    }
    for (int off = 32; off > 0; off >>= 1) {
        sA += __shfl_down(sA, off, 64);
        sB += __shfl_down(sB, off, 64);
    }
    if (lane == 0) {
        float m0 = sA / fmaxf((float)(i1 - i0), 1.0f);
        float m1 = sB / fmaxf((float)(i2 - i1), 1.0f);
        float logit = m0 + m1 + bptr[0];
        out[wave] = 1.0f / (1.0f + expf(-logit));
    }
}

extern "C" void kernel_launch(void* const* d_in, const int* in_sizes, int n_in,
                              void* d_out, int out_size, void* d_ws, size_t ws_size,
                              hipStream_t stream) {
    const float* emb         = (const float*)d_in[0];
    const float* W           = (const float*)d_in[1];
    const float* b           = (const float*)d_in[2];
    const int*   token_ids   = (const int*)d_in[3];
    const int*   segment_ids = (const int*)d_in[4];

    const int T     = in_sizes[3];
    const int vocab = in_sizes[0] / EMB;
    const int pairs = out_size;

    float* dotA = (float*)d_ws;
    float* dotB = dotA + vocab;

    // Kernel 1: 2048 blocks x 256 = 8192 waves (32/CU) over 100000 rows.
    dot_kernel<<<2048, 256, 0, stream>>>(emb, W, dotA, dotB, vocab);
    // Kernel 2: 16384 waves, 4 waves/block -> 4096 blocks.
    pair_kernel<<<(pairs * 64 + 255) / 256, 256, 0, stream>>>(
        token_ids, segment_ids, dotA, dotB, b, (float*)d_out, T, pairs);
}

// Round 4
// 44.149 us; speedup vs baseline: 3.1097x; 1.0459x over previous
//
#include <hip/hip_runtime.h>

#define EMB 300
#define EMB4 75  // 300/4

// Kernel 1: dot2[v] = (emb[v]·W[0:300], emb[v]·W[300:600]).
// Each 64-lane wave handles FOUR rows: 16-lane group g owns row 4*wave+g.
// Per group: 5 independent float4 loads (256B-contiguous per instruction),
// then a 4-step xor-shuffle reduce (stays within the 16-lane group).
__global__ void dot_kernel(const float* __restrict__ emb,
                           const float* __restrict__ W,
                           float2* __restrict__ dot2,
                           int vocab) {
    __shared__ float4 sWA[EMB4];
    __shared__ float4 sWB[EMB4];
    const float4* W4 = (const float4*)W;  // 600 floats = 150 float4
    for (int i = threadIdx.x; i < EMB4; i += blockDim.x) {
        sWA[i] = W4[i];
        sWB[i] = W4[EMB4 + i];
    }
    __syncthreads();

    int wave = (blockIdx.x * blockDim.x + threadIdx.x) >> 6;
    int lane = threadIdx.x & 63;
    int g    = lane >> 4;   // which of the wave's 4 rows
    int l    = lane & 15;   // lane within the 16-lane group

    int row = wave * 4 + g;
    bool active = (row < vocab);
    const float4* e4 = (const float4*)(emb + (size_t)(active ? row : 0) * EMB);

    float a = 0.f, b = 0.f;
    #pragma unroll
    for (int it = 0; it < 5; ++it) {
        int k = l + it * 16;
        if (active && k < EMB4) {
            float4 v  = e4[k];
            float4 wa = sWA[k];
            float4 wb = sWB[k];
            a += v.x * wa.x + v.y * wa.y + v.z * wa.z + v.w * wa.w;
            b += v.x * wb.x + v.y * wb.y + v.z * wb.z + v.w * wb.w;
        }
    }
    #pragma unroll
    for (int m = 8; m > 0; m >>= 1) {
        a += __shfl_xor(a, m, 64);
        b += __shfl_xor(b, m, 64);
    }
    if (active && l == 0) dot2[row] = make_float2(a, b);
}

__device__ __forceinline__ int lower_bound(const int* __restrict__ a, int n, int x) {
    int lo = 0, hi = n;
    while (lo < hi) {
        int mid = (lo + hi) >> 1;
        if (a[mid] < x) lo = mid + 1; else hi = mid;
    }
    return lo;
}

// Kernel 2: one wave per output pair. Lanes 0..2 binary-search the three
// segment boundaries, broadcast, then all lanes gather one float2 per token.
__global__ void pair_kernel(const int* __restrict__ token_ids,
                            const int* __restrict__ segment_ids,
                            const float2* __restrict__ dot2,
                            const float* __restrict__ bptr,
                            float* __restrict__ out,
                            int T, int pairs) {
    int wave = (blockIdx.x * blockDim.x + threadIdx.x) >> 6;
    int lane = threadIdx.x & 63;
    if (wave >= pairs) return;
    int s0 = 2 * wave;

    int bnd = 0;
    if (lane < 3) bnd = lower_bound(segment_ids, T, s0 + lane);
    int i0 = __shfl(bnd, 0, 64);
    int i1 = __shfl(bnd, 1, 64);
    int i2 = __shfl(bnd, 2, 64);

    float sA = 0.f, sB = 0.f;
    for (int j = i0 + lane; j < i2; j += 64) {
        float2 d = dot2[token_ids[j]];
        if (j < i1) sA += d.x; else sB += d.y;
    }
    for (int off = 32; off > 0; off >>= 1) {
        sA += __shfl_down(sA, off, 64);
        sB += __shfl_down(sB, off, 64);
    }
    if (lane == 0) {
        float m0 = sA / fmaxf((float)(i1 - i0), 1.0f);
        float m1 = sB / fmaxf((float)(i2 - i1), 1.0f);
        float logit = m0 + m1 + bptr[0];
        out[wave] = 1.0f / (1.0f + expf(-logit));
    }
}

extern "C" void kernel_launch(void* const* d_in, const int* in_sizes, int n_in,
                              void* d_out, int out_size, void* d_ws, size_t ws_size,
                              hipStream_t stream) {
    const float* emb         = (const float*)d_in[0];
    const float* W           = (const float*)d_in[1];
    const float* b           = (const float*)d_in[2];
    const int*   token_ids   = (const int*)d_in[3];
    const int*   segment_ids = (const int*)d_in[4];

    const int T     = in_sizes[3];
    const int vocab = in_sizes[0] / EMB;
    const int pairs = out_size;

    float2* dot2 = (float2*)d_ws;

    // Kernel 1: 4 rows per wave, 4 waves per block -> exact cover of vocab.
    int waves1  = (vocab + 3) / 4;
    int blocks1 = (waves1 + 3) / 4;
    dot_kernel<<<blocks1, 256, 0, stream>>>(emb, W, dot2, vocab);
    // Kernel 2: one wave per pair, 4 waves per block.
    pair_kernel<<<(pairs + 3) / 4, 256, 0, stream>>>(
        token_ids, segment_ids, dot2, b, (float*)d_out, T, pairs);
}

// Round 5
// 34.112 us; speedup vs baseline: 4.0247x; 1.2943x over previous
//
#include <hip/hip_runtime.h>

#define EMB 300
#define EMB4 75  // 300/4

// Fused kernel 1:
//   blocks [0, blocks_dot): dot2[v] = (emb[v]·W[0:300], emb[v]·W[300:600])
//     4 rows per wave (16-lane groups), float4 loads, xor-shuffle reduce.
//   blocks [blocks_dot, gridDim): boundary pass over sorted segment_ids:
//     bounds[s] = first token index with segment_ids >= s,  s in [0, nseg].
__global__ void fused1_kernel(const float* __restrict__ emb,
                              const float* __restrict__ W,
                              const int* __restrict__ segment_ids,
                              float2* __restrict__ dot2,
                              int* __restrict__ bounds,
                              int vocab, int T, int nseg, int blocks_dot) {
    if ((int)blockIdx.x < blocks_dot) {
        __shared__ float4 sWA[EMB4];
        __shared__ float4 sWB[EMB4];
        const float4* W4 = (const float4*)W;  // 600 floats = 150 float4
        for (int i = threadIdx.x; i < EMB4; i += blockDim.x) {
            sWA[i] = W4[i];
            sWB[i] = W4[EMB4 + i];
        }
        __syncthreads();

        int wave = (blockIdx.x * blockDim.x + threadIdx.x) >> 6;
        int lane = threadIdx.x & 63;
        int g    = lane >> 4;   // which of the wave's 4 rows
        int l    = lane & 15;   // lane within the 16-lane group

        int row = wave * 4 + g;
        bool active = (row < vocab);
        const float4* e4 = (const float4*)(emb + (size_t)(active ? row : 0) * EMB);

        float a = 0.f, b = 0.f;
        #pragma unroll
        for (int it = 0; it < 5; ++it) {
            int k = l + it * 16;
            if (active && k < EMB4) {
                float4 v  = e4[k];
                float4 wa = sWA[k];
                float4 wb = sWB[k];
                a += v.x * wa.x + v.y * wa.y + v.z * wa.z + v.w * wa.w;
                b += v.x * wb.x + v.y * wb.y + v.z * wb.z + v.w * wb.w;
            }
        }
        #pragma unroll
        for (int m = 8; m > 0; m >>= 1) {
            a += __shfl_xor(a, m, 64);
            b += __shfl_xor(b, m, 64);
        }
        if (active && l == 0) dot2[row] = make_float2(a, b);
    } else {
        // boundary pass: one streaming sweep of segment_ids
        int tid    = (blockIdx.x - blocks_dot) * blockDim.x + threadIdx.x;
        int stride = (gridDim.x - blocks_dot) * blockDim.x;
        for (int j = tid; j < T; j += stride) {
            int cur = segment_ids[j];
            if (j == 0) {
                for (int s = 0; s <= cur; ++s) bounds[s] = 0;
            } else {
                int prev = segment_ids[j - 1];
                for (int s = prev + 1; s <= cur; ++s) bounds[s] = j;
            }
            if (j == T - 1) {
                for (int s = cur + 1; s <= nseg; ++s) bounds[s] = T;
            }
        }
    }
}

// Kernel 2: one wave per output pair; boundaries read directly from bounds[].
__global__ void pair_kernel(const int* __restrict__ token_ids,
                            const int* __restrict__ bounds,
                            const float2* __restrict__ dot2,
                            const float* __restrict__ bptr,
                            float* __restrict__ out,
                            int pairs) {
    int wave = (blockIdx.x * blockDim.x + threadIdx.x) >> 6;
    int lane = threadIdx.x & 63;
    if (wave >= pairs) return;

    int i0 = bounds[2 * wave];
    int i1 = bounds[2 * wave + 1];
    int i2 = bounds[2 * wave + 2];

    float sA = 0.f, sB = 0.f;
    for (int j = i0 + lane; j < i2; j += 64) {
        float2 d = dot2[token_ids[j]];
        if (j < i1) sA += d.x; else sB += d.y;
    }
    for (int off = 32; off > 0; off >>= 1) {
        sA += __shfl_down(sA, off, 64);
        sB += __shfl_down(sB, off, 64);
    }
    if (lane == 0) {
        float m0 = sA / fmaxf((float)(i1 - i0), 1.0f);
        float m1 = sB / fmaxf((float)(i2 - i1), 1.0f);
        float logit = m0 + m1 + bptr[0];
        out[wave] = 1.0f / (1.0f + expf(-logit));
    }
}

extern "C" void kernel_launch(void* const* d_in, const int* in_sizes, int n_in,
                              void* d_out, int out_size, void* d_ws, size_t ws_size,
                              hipStream_t stream) {
    const float* emb         = (const float*)d_in[0];
    const float* W           = (const float*)d_in[1];
    const float* b           = (const float*)d_in[2];
    const int*   token_ids   = (const int*)d_in[3];
    const int*   segment_ids = (const int*)d_in[4];

    const int T     = in_sizes[3];
    const int vocab = in_sizes[0] / EMB;
    const int pairs = out_size;
    const int nseg  = pairs * 2;

    float2* dot2   = (float2*)d_ws;                 // 100000 * 8B = 800 KB
    int*    bounds = (int*)(dot2 + vocab);          // 32769 * 4B

    // dot part: 4 rows/wave, 4 waves/block -> 6250 blocks cover 100000 rows.
    int waves1     = (vocab + 3) / 4;
    int blocks_dot = (waves1 + 3) / 4;
    int blocks_bnd = 512;  // streaming boundary pass, grid-stride over T
    fused1_kernel<<<blocks_dot + blocks_bnd, 256, 0, stream>>>(
        emb, W, segment_ids, dot2, bounds, vocab, T, nseg, blocks_dot);

    // one wave per pair, 4 waves per block.
    pair_kernel<<<(pairs + 3) / 4, 256, 0, stream>>>(
        token_ids, bounds, dot2, b, (float*)d_out, pairs);
}

// Round 6
// 32.889 us; speedup vs baseline: 4.1743x; 1.0372x over previous
//
#include <hip/hip_runtime.h>

#define EMB 300
#define EMB4 75  // 300/4

// Fused kernel 1:
//   blocks [0, blocks_dot): dot2[v] = (emb[v]·W[0:300], emb[v]·W[300:600])
//     Persistent grid-stride waves; each wave owns 4 rows per iteration
//     (one per 16-lane group), 5 float4 loads/lane/row, W held in registers.
//   blocks [blocks_dot, gridDim): boundary pass over sorted segment_ids:
//     bounds[s] = first token index with segment_ids >= s, s in [0, nseg].
__global__ void fused1_kernel(const float* __restrict__ emb,
                              const float* __restrict__ W,
                              const int* __restrict__ segment_ids,
                              float2* __restrict__ dot2,
                              int* __restrict__ bounds,
                              int vocab, int T, int nseg, int blocks_dot) {
    if ((int)blockIdx.x < blocks_dot) {
        const float4* W4 = (const float4*)W;  // 600 floats = 150 float4
        int wave   = (blockIdx.x * blockDim.x + threadIdx.x) >> 6;
        int nwaves = (blocks_dot * blockDim.x) >> 6;
        int lane   = threadIdx.x & 63;
        int g      = lane >> 4;   // group: which of the wave's 4 rows
        int l      = lane & 15;   // lane within the 16-lane group

        // Hoist W into registers: lane l always covers k = l + 16*it.
        float4 wa[5], wb[5];
        #pragma unroll
        for (int it = 0; it < 5; ++it) {
            int k = l + it * 16;
            if (k < EMB4) {
                wa[it] = W4[k];
                wb[it] = W4[EMB4 + k];
            } else {
                wa[it] = make_float4(0.f, 0.f, 0.f, 0.f);
                wb[it] = make_float4(0.f, 0.f, 0.f, 0.f);
            }
        }

        int ngroups = (vocab + 3) >> 2;  // row-groups of 4
        for (int rg = wave; rg < ngroups; rg += nwaves) {
            int row = rg * 4 + g;
            bool active = (row < vocab);
            const float4* e4 =
                (const float4*)(emb + (size_t)(active ? row : 0) * EMB);

            float a = 0.f, b = 0.f;
            #pragma unroll
            for (int it = 0; it < 5; ++it) {
                int k = l + it * 16;
                if (active && k < EMB4) {
                    float4 v = e4[k];
                    a += v.x * wa[it].x + v.y * wa[it].y +
                         v.z * wa[it].z + v.w * wa[it].w;
                    b += v.x * wb[it].x + v.y * wb[it].y +
                         v.z * wb[it].z + v.w * wb[it].w;
                }
            }
            #pragma unroll
            for (int m = 8; m > 0; m >>= 1) {
                a += __shfl_xor(a, m, 64);
                b += __shfl_xor(b, m, 64);
            }
            if (active && l == 0) dot2[row] = make_float2(a, b);
        }
    } else {
        // boundary pass: one streaming sweep of segment_ids
        int tid    = (blockIdx.x - blocks_dot) * blockDim.x + threadIdx.x;
        int stride = (gridDim.x - blocks_dot) * blockDim.x;
        for (int j = tid; j < T; j += stride) {
            int cur = segment_ids[j];
            if (j == 0) {
                for (int s = 0; s <= cur; ++s) bounds[s] = 0;
            } else {
                int prev = segment_ids[j - 1];
                for (int s = prev + 1; s <= cur; ++s) bounds[s] = j;
            }
            if (j == T - 1) {
                for (int s = cur + 1; s <= nseg; ++s) bounds[s] = T;
            }
        }
    }
}

// Kernel 2: one wave per output pair; boundaries read directly from bounds[].
__global__ void pair_kernel(const int* __restrict__ token_ids,
                            const int* __restrict__ bounds,
                            const float2* __restrict__ dot2,
                            const float* __restrict__ bptr,
                            float* __restrict__ out,
                            int pairs) {
    int wave = (blockIdx.x * blockDim.x + threadIdx.x) >> 6;
    int lane = threadIdx.x & 63;
    if (wave >= pairs) return;

    int i0 = bounds[2 * wave];
    int i1 = bounds[2 * wave + 1];
    int i2 = bounds[2 * wave + 2];

    float sA = 0.f, sB = 0.f;
    for (int j = i0 + lane; j < i2; j += 64) {
        float2 d = dot2[token_ids[j]];
        if (j < i1) sA += d.x; else sB += d.y;
    }
    for (int off = 32; off > 0; off >>= 1) {
        sA += __shfl_down(sA, off, 64);
        sB += __shfl_down(sB, off, 64);
    }
    if (lane == 0) {
        float m0 = sA / fmaxf((float)(i1 - i0), 1.0f);
        float m1 = sB / fmaxf((float)(i2 - i1), 1.0f);
        float logit = m0 + m1 + bptr[0];
        out[wave] = 1.0f / (1.0f + expf(-logit));
    }
}

extern "C" void kernel_launch(void* const* d_in, const int* in_sizes, int n_in,
                              void* d_out, int out_size, void* d_ws, size_t ws_size,
                              hipStream_t stream) {
    const float* emb         = (const float*)d_in[0];
    const float* W           = (const float*)d_in[1];
    const float* b           = (const float*)d_in[2];
    const int*   token_ids   = (const int*)d_in[3];
    const int*   segment_ids = (const int*)d_in[4];

    const int T     = in_sizes[3];
    const int vocab = in_sizes[0] / EMB;
    const int pairs = out_size;
    const int nseg  = pairs * 2;

    float2* dot2   = (float2*)d_ws;                 // 100000 * 8B = 800 KB
    int*    bounds = (int*)(dot2 + vocab);          // 32769 * 4B

    // dot part: persistent waves, ~6 row-groups per wave.
    int blocks_dot = 1024;
    int blocks_bnd = 256;  // streaming boundary pass, grid-stride over T
    fused1_kernel<<<blocks_dot + blocks_bnd, 256, 0, stream>>>(
        emb, W, segment_ids, dot2, bounds, vocab, T, nseg, blocks_dot);

    // one wave per pair, 4 waves per block.
    pair_kernel<<<(pairs + 3) / 4, 256, 0, stream>>>(
        token_ids, bounds, dot2, b, (float*)d_out, pairs);
}